// Round 1
// baseline (842.284 us; speedup 1.0000x reference)
//
#include <hip/hip_runtime.h>
#include <math.h>

#define NN 10000
#define EE 320000

__device__ __forceinline__ float lrelu02(float x) { return x > 0.f ? x : 0.2f * x; }

// ---------------- CSR build ----------------
__global__ void k_hist(const int* __restrict__ ei, int* __restrict__ deg) {
    int e = blockIdx.x * 256 + threadIdx.x;
    if (e < EE) atomicAdd(&deg[ei[EE + e]], 1);
}

__global__ void k_scan(const int* __restrict__ deg, int* __restrict__ off) {
    __shared__ int wsum[16];
    __shared__ int carry;
    int tid = threadIdx.x, lane = tid & 63, wid = tid >> 6;
    if (tid == 0) { carry = 0; off[0] = 0; }
    __syncthreads();
    for (int base = 0; base < NN; base += 1024) {
        int i = base + tid;
        int v = (i < NN) ? deg[i] : 0;
        int x = v;
        #pragma unroll
        for (int o = 1; o < 64; o <<= 1) {
            int y = __shfl_up(x, o);
            if (lane >= o) x += y;
        }
        if (lane == 63) wsum[wid] = x;
        __syncthreads();
        if (wid == 0) {
            int w = (lane < 16) ? wsum[lane] : 0;
            #pragma unroll
            for (int o = 1; o < 16; o <<= 1) {
                int y = __shfl_up(w, o);
                if (lane >= o) w += y;
            }
            if (lane < 16) wsum[lane] = w;
        }
        __syncthreads();
        int pre = (wid > 0) ? wsum[wid - 1] : 0;
        int incl = x + pre + carry;
        if (i < NN) off[i + 1] = incl;
        __syncthreads();
        if (tid == 1023) carry = incl;
        __syncthreads();
    }
}

__global__ void k_scatter(const int* __restrict__ ei, int* __restrict__ cur,
                          int* __restrict__ csr) {
    int e = blockIdx.x * 256 + threadIdx.x;
    if (e < EE) {
        int s = ei[e], d = ei[EE + e];
        int p = atomicAdd(&cur[d], 1);
        csr[p] = s;
    }
}

// ---------------- fused GEMM (+bias+LN+act) ----------------
// ACT: 0 none, 1 relu, 2 tanh(relu)
template <int K, int NOUT, int ACT, bool FUSED>
__global__ __launch_bounds__(256) void k_gemm(const float* __restrict__ A,
                                              const float* __restrict__ W,
                                              const float* __restrict__ bias,
                                              const float* __restrict__ gamma,
                                              const float* __restrict__ beta,
                                              float* __restrict__ out) {
    constexpr int GR = 16;
    constexpr int CPT = NOUT > 256 ? NOUT / 256 : 1;
    constexpr int ACTIVE = NOUT > 256 ? 256 : NOUT;
    constexpr int SW = (K > 256 ? K : 256);
    __shared__ float smem[GR * SW];
    __shared__ float rstat[2 * GR];
    int tid = threadIdx.x;
    long row0 = (long)blockIdx.x * GR;

    // cooperative load of 16 A rows (contiguous) into LDS
    {
        const float4* Ar = (const float4*)(A + row0 * K);
        float4* S4 = (float4*)smem;
        constexpr int NV = GR * K / 4;
        for (int idx = tid; idx < NV; idx += 256) S4[idx] = Ar[idx];
    }
    __syncthreads();

    float acc[GR][CPT];
    #pragma unroll
    for (int r = 0; r < GR; ++r)
        #pragma unroll
        for (int c = 0; c < CPT; ++c) acc[r][c] = 0.f;

    if (tid < ACTIVE) {
        #pragma unroll 4
        for (int k = 0; k < K; ++k) {
            float w[CPT];
            #pragma unroll
            for (int c = 0; c < CPT; ++c) w[c] = W[(long)k * NOUT + tid + c * 256];
            #pragma unroll
            for (int r = 0; r < GR; ++r) {
                float a = smem[r * K + k];
                #pragma unroll
                for (int c = 0; c < CPT; ++c) acc[r][c] += a * w[c];
            }
        }
    }

    if constexpr (!FUSED) {
        if (tid < ACTIVE) {
            #pragma unroll
            for (int r = 0; r < GR; ++r)
                #pragma unroll
                for (int c = 0; c < CPT; ++c)
                    out[(row0 + r) * NOUT + tid + c * 256] = acc[r][c];
        }
        return;
    } else {
        float gg[CPT], be[CPT];
        if (tid < ACTIVE) {
            #pragma unroll
            for (int c = 0; c < CPT; ++c) {
                float bb = bias[tid + c * 256];
                gg[c] = gamma[tid + c * 256];
                be[c] = beta[tid + c * 256];
                #pragma unroll
                for (int r = 0; r < GR; ++r) acc[r][c] += bb;
            }
        }
        __syncthreads();  // done with As region, reuse as reduction scratch

        // row sums
        for (int r = 0; r < GR; ++r) {
            float p = 0.f;
            if (tid < ACTIVE)
                #pragma unroll
                for (int c = 0; c < CPT; ++c) p += acc[r][c];
            smem[r * 256 + tid] = p;
        }
        __syncthreads();
        int wid = tid >> 6, lane = tid & 63;
        for (int r = wid; r < GR; r += 4) {
            float s = smem[r * 256 + lane] + smem[r * 256 + lane + 64] +
                      smem[r * 256 + lane + 128] + smem[r * 256 + lane + 192];
            #pragma unroll
            for (int o = 32; o > 0; o >>= 1) s += __shfl_down(s, o);
            if (lane == 0) rstat[r] = s;
        }
        __syncthreads();
        // row sum of squared deviations
        for (int r = 0; r < GR; ++r) {
            float mu = rstat[r] * (1.f / NOUT);
            float p = 0.f;
            if (tid < ACTIVE)
                #pragma unroll
                for (int c = 0; c < CPT; ++c) {
                    float d = acc[r][c] - mu;
                    p += d * d;
                }
            smem[r * 256 + tid] = p;
        }
        __syncthreads();
        for (int r = wid; r < GR; r += 4) {
            float s = smem[r * 256 + lane] + smem[r * 256 + lane + 64] +
                      smem[r * 256 + lane + 128] + smem[r * 256 + lane + 192];
            #pragma unroll
            for (int o = 32; o > 0; o >>= 1) s += __shfl_down(s, o);
            if (lane == 0) rstat[GR + r] = s;
        }
        __syncthreads();
        if (tid < ACTIVE) {
            #pragma unroll
            for (int r = 0; r < GR; ++r) {
                float mu = rstat[r] * (1.f / NOUT);
                float rs = rsqrtf(rstat[GR + r] * (1.f / NOUT) + 1e-5f);
                #pragma unroll
                for (int c = 0; c < CPT; ++c) {
                    float v = (acc[r][c] - mu) * rs * gg[c] + be[c];
                    if (ACT == 1) v = fmaxf(v, 0.f);
                    if (ACT == 2) v = tanhf(fmaxf(v, 0.f));
                    out[(row0 + r) * NOUT + tid + c * 256] = v;
                }
            }
        }
    }
}

// ---------------- attention vectors ----------------
__device__ __forceinline__ float dot4(float4 a, float4 b) {
    return a.x * b.x + a.y * b.y + a.z * b.z + a.w * b.w;
}

__global__ __launch_bounds__(256) void k_attvec(const float* __restrict__ h,
                                                const float* __restrict__ att_s,
                                                const float* __restrict__ att_d,
                                                float* __restrict__ asrc,
                                                float* __restrict__ adst) {
    int wid = threadIdx.x >> 6, lane = threadIdx.x & 63;
    int n = blockIdx.x * 4 + wid;
    if (n >= NN) return;
    const float4* hr = (const float4*)(h + (long)n * 512);
    float4 v0 = hr[lane], v1 = hr[lane + 64];
    float4 a0 = ((const float4*)att_s)[lane];
    float4 a1 = ((const float4*)att_s)[lane + 64];
    float4 b0 = ((const float4*)att_d)[lane];
    float4 b1 = ((const float4*)att_d)[lane + 64];
    float s0 = dot4(v0, a0), s1 = dot4(v1, a1);
    float d0 = dot4(v0, b0), d1 = dot4(v1, b1);
    #pragma unroll
    for (int o = 32; o > 0; o >>= 1) {
        s0 += __shfl_down(s0, o);
        s1 += __shfl_down(s1, o);
        d0 += __shfl_down(d0, o);
        d1 += __shfl_down(d1, o);
    }
    if (lane == 0) {
        asrc[2 * n] = s0; asrc[2 * n + 1] = s1;
        adst[2 * n] = d0; adst[2 * n + 1] = d1;
    }
}

// ---------------- block reduce helpers ----------------
__device__ __forceinline__ float bredmax(float v, volatile float* sm) {
    #pragma unroll
    for (int o = 32; o > 0; o >>= 1) v = fmaxf(v, __shfl_down(v, o));
    int wid = threadIdx.x >> 6, lane = threadIdx.x & 63;
    __syncthreads();
    if (lane == 0) sm[wid] = v;
    __syncthreads();
    return fmaxf(fmaxf(sm[0], sm[1]), fmaxf(sm[2], sm[3]));
}

__device__ __forceinline__ float bredsum(float v, volatile float* sm) {
    #pragma unroll
    for (int o = 32; o > 0; o >>= 1) v += __shfl_down(v, o);
    int wid = threadIdx.x >> 6, lane = threadIdx.x & 63;
    __syncthreads();
    if (lane == 0) sm[wid] = v;
    __syncthreads();
    return sm[0] + sm[1] + sm[2] + sm[3];
}

// ---------------- GAT aggregate (per-dst block) ----------------
__global__ __launch_bounds__(256) void k_agg(const int* __restrict__ csr,
                                             const int* __restrict__ off,
                                             const float* __restrict__ h,
                                             const float* __restrict__ asrc,
                                             const float* __restrict__ adst,
                                             const float* __restrict__ bg,
                                             float* __restrict__ h1) {
    __shared__ float sm[4];
    int n = blockIdx.x, tid = threadIdx.x;
    int beg = off[n], end = off[n + 1];
    float ad0 = adst[2 * n], ad1 = adst[2 * n + 1];
    float ls0 = lrelu02(asrc[2 * n] + ad0);    // self-loop logits
    float ls1 = lrelu02(asrc[2 * n + 1] + ad1);

    // pass 1: max
    float m0 = ls0, m1 = ls1;
    for (int e = beg + tid; e < end; e += 256) {
        int s = csr[e];
        m0 = fmaxf(m0, lrelu02(asrc[2 * s] + ad0));
        m1 = fmaxf(m1, lrelu02(asrc[2 * s + 1] + ad1));
    }
    m0 = bredmax(m0, sm);
    m1 = bredmax(m1, sm);

    // pass 2: denom
    float z0 = 0.f, z1 = 0.f;
    if (tid == 0) { z0 = __expf(ls0 - m0); z1 = __expf(ls1 - m1); }
    for (int e = beg + tid; e < end; e += 256) {
        int s = csr[e];
        z0 += __expf(lrelu02(asrc[2 * s] + ad0) - m0);
        z1 += __expf(lrelu02(asrc[2 * s + 1] + ad1) - m1);
    }
    z0 = bredsum(z0, sm);
    z1 = bredsum(z1, sm);
    float inv0 = 1.f / (z0 + 1e-16f);
    float inv1 = 1.f / (z1 + 1e-16f);

    // pass 3: weighted accumulate; thread owns channels tid (head0), tid+256 (head1)
    int c0 = tid, c1 = tid + 256;
    float acc0 = __expf(ls0 - m0) * inv0 * h[(long)n * 512 + c0];
    float acc1 = __expf(ls1 - m1) * inv1 * h[(long)n * 512 + c1];
    for (int e = beg; e < end; ++e) {
        int s = csr[e];
        float al0 = __expf(lrelu02(asrc[2 * s] + ad0) - m0) * inv0;
        float al1 = __expf(lrelu02(asrc[2 * s + 1] + ad1) - m1) * inv1;
        const float* hs = h + (long)s * 512;
        acc0 += al0 * hs[c0];
        acc1 += al1 * hs[c1];
    }
    h1[(long)n * 512 + c0] = fmaxf(acc0 + bg[c0], 0.f);
    h1[(long)n * 512 + c1] = fmaxf(acc1 + bg[c1], 0.f);
}

// ---------------- final tiny layer + point packing ----------------
__global__ __launch_bounds__(256) void k_final(const float* __restrict__ h4,
                                               const float* __restrict__ W3,
                                               const float* __restrict__ b3,
                                               float4* __restrict__ pts) {
    int n = blockIdx.x * 256 + threadIdx.x;
    if (n >= NN) return;
    float o0 = b3[0], o1 = b3[1], o2 = b3[2];
    const float* row = h4 + (long)n * 64;
    #pragma unroll 8
    for (int k = 0; k < 64; ++k) {
        float v = row[k];
        o0 += v * W3[k * 3 + 0];
        o1 += v * W3[k * 3 + 1];
        o2 += v * W3[k * 3 + 2];
    }
    float sq = o0 * o0 + o1 * o1 + o2 * o2;
    pts[n] = make_float4(o0, o1, o2, sq);
}

// ---------------- pairwise distances ----------------
__global__ __launch_bounds__(256) void k_cdist(const float4* __restrict__ pts,
                                               float* __restrict__ out) {
    __shared__ float4 spi[8];
    int i0 = blockIdx.y * 8;
    int j = blockIdx.x * 256 + threadIdx.x;
    if (threadIdx.x < 8) spi[threadIdx.x] = pts[i0 + threadIdx.x];
    __syncthreads();
    if (j >= NN) return;
    float4 pj = pts[j];
    #pragma unroll
    for (int r = 0; r < 8; ++r) {
        float dx = spi[r].x - pj.x;
        float dy = spi[r].y - pj.y;
        float dz = spi[r].z - pj.z;
        float d2 = dx * dx + dy * dy + dz * dz;
        out[(long)(i0 + r) * NN + j] = d2 > 0.f ? sqrtf(d2) : 0.f;
    }
}

// ---------------- launch ----------------
extern "C" void kernel_launch(void* const* d_in, const int* in_sizes, int n_in,
                              void* d_out, int out_size, void* d_ws, size_t ws_size,
                              hipStream_t stream) {
    const float* x     = (const float*)d_in[0];
    const int*   ei    = (const int*)d_in[1];
    const float* Wg    = (const float*)d_in[2];
    const float* att_s = (const float*)d_in[3];
    const float* att_d = (const float*)d_in[4];
    const float* bg    = (const float*)d_in[5];
    const float* Wa    = (const float*)d_in[6];
    const float* ba    = (const float*)d_in[7];
    const float* ga    = (const float*)d_in[8];
    const float* bna   = (const float*)d_in[9];
    const float* W1    = (const float*)d_in[10];
    const float* b1    = (const float*)d_in[11];
    const float* g1    = (const float*)d_in[12];
    const float* bn1   = (const float*)d_in[13];
    const float* W2    = (const float*)d_in[14];
    const float* b2    = (const float*)d_in[15];
    const float* g2    = (const float*)d_in[16];
    const float* bn2   = (const float*)d_in[17];
    const float* W3    = (const float*)d_in[18];
    const float* b3    = (const float*)d_in[19];

    char* p = (char*)d_ws;
    auto alloc = [&](size_t bytes) {
        void* q = (void*)p;
        p += (bytes + 255) & ~(size_t)255;
        return q;
    };
    float* bufA = (float*)alloc((size_t)NN * 512 * 4);  // h, then h2, then h4
    float* bufB = (float*)alloc((size_t)NN * 512 * 4);  // h1, then h3
    float* pts  = (float*)alloc((size_t)NN * 4 * 4);
    float* asrc = (float*)alloc((size_t)NN * 2 * 4);
    float* adst = (float*)alloc((size_t)NN * 2 * 4);
    int* deg    = (int*)alloc((size_t)(NN + 1) * 4);
    int* off    = (int*)alloc((size_t)(NN + 1) * 4);
    int* cur    = (int*)alloc((size_t)NN * 4);
    int* csr    = (int*)alloc((size_t)EE * 4);

    float* h  = bufA;
    float* h1 = bufB;
    float* h2 = bufA;  // h dead after k_agg
    float* h3 = bufB;  // h1 dead after layer A
    float* h4 = bufA;  // h2 dead after layer 1

    hipMemsetAsync(deg, 0, (size_t)(NN + 1) * 4, stream);
    k_hist<<<(EE + 255) / 256, 256, 0, stream>>>(ei, deg);
    k_scan<<<1, 1024, 0, stream>>>(deg, off);
    hipMemcpyAsync(cur, off, (size_t)NN * 4, hipMemcpyDeviceToDevice, stream);
    k_scatter<<<(EE + 255) / 256, 256, 0, stream>>>(ei, cur, csr);

    k_gemm<512, 512, 0, false><<<625, 256, 0, stream>>>(x, Wg, nullptr, nullptr, nullptr, h);
    k_attvec<<<2500, 256, 0, stream>>>(h, att_s, att_d, asrc, adst);
    k_agg<<<NN, 256, 0, stream>>>(csr, off, h, asrc, adst, bg, h1);

    k_gemm<512, 256, 1, true><<<625, 256, 0, stream>>>(h1, Wa, ba, ga, bna, h2);
    k_gemm<256, 128, 2, true><<<625, 256, 0, stream>>>(h2, W1, b1, g1, bn1, h3);
    k_gemm<128, 64, 1, true><<<625, 256, 0, stream>>>(h3, W2, b2, g2, bn2, h4);
    k_final<<<(NN + 255) / 256, 256, 0, stream>>>(h4, W3, b3, (float4*)pts);

    k_cdist<<<dim3(40, 1250), 256, 0, stream>>>((const float4*)pts, (float*)d_out);
}